// Round 8
// baseline (609.066 us; speedup 1.0000x reference)
//
#include <hip/hip_runtime.h>
#include <math.h>

#define ALPHA_F 0.02f

constexpr int Bn  = 32;
constexpr int Cn  = 512;
constexpr int CRn = 32;    // C / 16
constexpr int HWn = 4096;  // 64*64
constexpr int NCG = 8;     // channel groups of 64 channels
constexpr int NPG = 4;     // pixel groups of 1024 pixels

typedef float floatx4 __attribute__((ext_vector_type(4)));

__device__ __forceinline__ float sigmoidf_(float v) {
    return 1.0f / (1.0f + expf(-v));
}

// ---------------------------------------------------------------------------
// K1-mega: the K1 body repeated REP1 times inside ONE dispatch (identical
// output each rep) so the dispatch exceeds the harness fills and surfaces
// per-kernel counters (FETCH/VALUBusy). DIAGNOSTIC ROUND.
// ---------------------------------------------------------------------------
constexpr int REP1 = 6;

__global__ __launch_bounds__(256) void k1_mega(
    const float* __restrict__ x,
    float* __restrict__ cps, float* __restrict__ cpm,
    float* __restrict__ sps, float* __restrict__ spm)
{
    const int bid = blockIdx.x;
    const int pg  = bid & 3;
    const int cg  = (bid >> 2) & 7;
    const int b   = bid >> 5;
    const int t    = threadIdx.x;
    const int wv   = t >> 6;
    const int lane = t & 63;

    __shared__ float ls[4][1024];
    __shared__ float lm[4][1024];

    const float* xb = x + ((size_t)b * Cn + (size_t)cg * 64) * HWn + pg * 1024;

    for (int rep = 0; rep < REP1; ++rep) {
        asm volatile("" ::: "memory");
        float4 psum[4], pmax[4];
#pragma unroll
        for (int q = 0; q < 4; ++q) {
            psum[q] = make_float4(0.f, 0.f, 0.f, 0.f);
            pmax[q] = make_float4(-INFINITY, -INFINITY, -INFINITY, -INFINITY);
        }

#pragma unroll 4
        for (int cl = 0; cl < 16; ++cl) {
            const int c = wv * 16 + cl;
            const float4* row = (const float4*)(xb + (size_t)c * HWn);
            float lsum = 0.f, lmax = -INFINITY;
#pragma unroll
            for (int q = 0; q < 4; ++q) {
                const float4 v = row[q * 64 + lane];
                psum[q].x += v.x; psum[q].y += v.y; psum[q].z += v.z; psum[q].w += v.w;
                pmax[q].x = fmaxf(pmax[q].x, v.x);
                pmax[q].y = fmaxf(pmax[q].y, v.y);
                pmax[q].z = fmaxf(pmax[q].z, v.z);
                pmax[q].w = fmaxf(pmax[q].w, v.w);
                lsum += (v.x + v.y) + (v.z + v.w);
                lmax = fmaxf(lmax, fmaxf(fmaxf(v.x, v.y), fmaxf(v.z, v.w)));
            }
#pragma unroll
            for (int m = 32; m >= 1; m >>= 1) {
                lsum += __shfl_xor(lsum, m, 64);
                lmax = fmaxf(lmax, __shfl_xor(lmax, m, 64));
            }
            if (lane == 0) {
                const int cglob = cg * 64 + c;
                cps[(pg * Bn + b) * Cn + cglob] = lsum;
                cpm[(pg * Bn + b) * Cn + cglob] = lmax;
            }
        }

        float4* lsw = (float4*)ls[wv];
        float4* lmw = (float4*)lm[wv];
#pragma unroll
        for (int q = 0; q < 4; ++q) {
            lsw[q * 64 + lane] = psum[q];
            lmw[q * 64 + lane] = pmax[q];
        }
        __syncthreads();

        float4 s  = ((const float4*)ls[0])[t];
        float4 mx = ((const float4*)lm[0])[t];
#pragma unroll
        for (int w = 1; w < 4; ++w) {
            const float4 a  = ((const float4*)ls[w])[t];
            const float4 bb = ((const float4*)lm[w])[t];
            s.x += a.x; s.y += a.y; s.z += a.z; s.w += a.w;
            mx.x = fmaxf(mx.x, bb.x); mx.y = fmaxf(mx.y, bb.y);
            mx.z = fmaxf(mx.z, bb.z); mx.w = fmaxf(mx.w, bb.w);
        }
        float4* os = (float4*)(sps + ((size_t)cg * Bn + b) * HWn + pg * 1024);
        float4* om = (float4*)(spm + ((size_t)cg * Bn + b) * HWn + pg * 1024);
        os[t] = s;
        om[t] = mx;
        __syncthreads();
    }
}

// ---------------------------------------------------------------------------
// K_mid (unchanged from R7)
// ---------------------------------------------------------------------------
__global__ __launch_bounds__(256) void k_mid(
    const float* __restrict__ sps, const float* __restrict__ spm,
    const float* __restrict__ cps, const float* __restrict__ cpm,
    const float* __restrict__ w1, const float* __restrict__ w2,
    const float* __restrict__ wconv,
    float* __restrict__ mcF, float* __restrict__ msF)
{
    const int b = blockIdx.x >> 3;
    const int s = blockIdx.x & 7;
    const int t = threadIdx.x;

    __shared__ float wsa[14][64];
    __shared__ float wsm[14][64];
    __shared__ float avg[Cn];
    __shared__ float mxv[Cn];
    __shared__ float hs[CRn];
    __shared__ float wc[98];
    if (t < 98) wc[t] = wconv[t];

    const int ybase = s * 8 - 3;
    {
        const int cgstep = Bn * HWn;
        const float inv = 1.0f / (float)Cn;
#pragma unroll
        for (int k = 0; k < 4; ++k) {
            const int i = t + 256 * k;
            if (i < 14 * 64) {
                const int rw  = i >> 6;
                const int col = i & 63;
                const int yw  = ybase + rw;
                if ((unsigned)yw < 64u) {
                    const int p = (yw << 6) + col;
                    const float* ps = sps + (size_t)b * HWn + p;
                    const float* pm = spm + (size_t)b * HWn + p;
                    float sv = ps[0], mv = pm[0];
#pragma unroll
                    for (int cg = 1; cg < NCG; ++cg) {
                        sv += ps[(size_t)cg * cgstep];
                        mv = fmaxf(mv, pm[(size_t)cg * cgstep]);
                    }
                    wsa[rw][col] = sv * inv;
                    wsm[rw][col] = mv;
                } else {
                    wsa[rw][col] = 0.f;
                    wsm[rw][col] = 0.f;
                }
            }
        }
    }

    if (s == 0) {
        for (int c = t; c < Cn; c += 256) {
            float sv = 0.f, mv = -INFINITY;
#pragma unroll
            for (int pgi = 0; pgi < NPG; ++pgi) {
                sv += cps[(pgi * Bn + b) * Cn + c];
                mv = fmaxf(mv, cpm[(pgi * Bn + b) * Cn + c]);
            }
            avg[c] = sv * (1.0f / (float)HWn);
            mxv[c] = mv;
        }
        __syncthreads();

        const int j = t >> 3, s8 = t & 7;
        float pa = 0.f, pm2 = 0.f;
        const float* w1r = w1 + j * Cn + s8 * 64;
        const float* av  = avg + s8 * 64;
        const float* mv  = mxv + s8 * 64;
        for (int k = 0; k < 64; ++k) {
            pa  += av[k] * w1r[k];
            pm2 += mv[k] * w1r[k];
        }
        pa += __shfl_xor(pa, 1, 64); pm2 += __shfl_xor(pm2, 1, 64);
        pa += __shfl_xor(pa, 2, 64); pm2 += __shfl_xor(pm2, 2, 64);
        pa += __shfl_xor(pa, 4, 64); pm2 += __shfl_xor(pm2, 4, 64);
        if (s8 == 0) hs[j] = fmaxf(pa, 0.f) + fmaxf(pm2, 0.f);
        __syncthreads();

        for (int c = t; c < Cn; c += 256) {
            float o = 0.f;
            const float* w2r = w2 + c * CRn;
#pragma unroll
            for (int jj = 0; jj < CRn; ++jj) o += hs[jj] * w2r[jj];
            mcF[b * Cn + c] = 1.0f - ALPHA_F + ALPHA_F * sigmoidf_(o);
        }
    } else {
        __syncthreads();
        __syncthreads();
    }
    __syncthreads();

#pragma unroll
    for (int k = 0; k < 2; ++k) {
        const int pl  = t + 256 * k;
        const int ry  = pl >> 6;
        const int col = pl & 63;
        const int yown = s * 8 + ry;
        float acc = 0.f;
#pragma unroll
        for (int ky = 0; ky < 7; ++ky) {
            const int yy = yown + ky - 3;
            if ((unsigned)yy >= 64u) continue;
            const int rw = ry + ky;
#pragma unroll
            for (int kx = 0; kx < 7; ++kx) {
                const int xx = col + kx - 3;
                if ((unsigned)xx >= 64u) continue;
                acc += wc[ky * 7 + kx] * wsa[rw][xx]
                     + wc[49 + ky * 7 + kx] * wsm[rw][xx];
            }
        }
        msF[b * HWn + (yown << 6) + col] = 1.0f - ALPHA_F + ALPHA_F * sigmoidf_(acc);
    }
}

// ---------------------------------------------------------------------------
// K4-mega: the K4 body repeated REP4 times in ONE dispatch. Identical output
// each rep. DIAGNOSTIC: FETCH tells whether x is L3-served; WRITE/dur gives
// the NT store ceiling.
// ---------------------------------------------------------------------------
constexpr int REP4 = 4;

__global__ __launch_bounds__(256) void k4_mega(
    const float* __restrict__ x, const float* __restrict__ mcF,
    const float* __restrict__ msF, float* __restrict__ out)
{
    const int bid = blockIdx.x;
    const int pg  = bid & 3;
    const int cg  = (bid >> 2) & 7;
    const int b   = bid >> 5;
    const int t   = threadIdx.x;

    const size_t chunk_off = ((size_t)b * Cn + (size_t)cg * 64) * HWn + pg * 1024;
    const float* xb = x + chunk_off;
    float* ob = out + chunk_off;

    const floatx4 msv = ((const floatx4*)(msF + (size_t)b * HWn + pg * 1024))[t];
    const float* mcRow = mcF + b * Cn + cg * 64;

    for (int rep = 0; rep < REP4; ++rep) {
        asm volatile("" ::: "memory");
#pragma unroll 8
        for (int r = 0; r < 64; ++r) {
            const floatx4 xv = ((const floatx4*)(xb + (size_t)r * HWn))[t];
            const floatx4 res = xv * (mcRow[r] * msv);
            __builtin_nontemporal_store(res, ((floatx4*)(ob + (size_t)r * HWn)) + t);
        }
    }
}

extern "C" void kernel_launch(void* const* d_in, const int* in_sizes, int n_in,
                              void* d_out, int out_size, void* d_ws, size_t ws_size,
                              hipStream_t stream)
{
    const float* x     = (const float*)d_in[0];
    const float* w1    = (const float*)d_in[1];
    const float* w2    = (const float*)d_in[2];
    const float* wconv = (const float*)d_in[3];
    float* out = (float*)d_out;

    float* p = (float*)d_ws;
    float* cps  = p; p += NPG * Bn * Cn;   // 65536
    float* cpm  = p; p += NPG * Bn * Cn;   // 65536
    float* sps  = p; p += NCG * Bn * HWn;  // 1048576
    float* spm  = p; p += NCG * Bn * HWn;  // 1048576
    float* mcF  = p; p += Bn * Cn;         // 16384
    float* msF  = p; p += Bn * HWn;        // 131072

    hipLaunchKernelGGL(k1_mega, dim3(Bn * NCG * NPG), dim3(256), 0, stream,
                       x, cps, cpm, sps, spm);
    hipLaunchKernelGGL(k_mid, dim3(Bn * 8), dim3(256), 0, stream,
                       sps, spm, cps, cpm, w1, w2, wconv, mcF, msF);
    hipLaunchKernelGGL(k4_mega, dim3(Bn * NCG * NPG), dim3(256), 0, stream,
                       x, mcF, msF, out);
}

// Round 9
// 168.406 us; speedup vs baseline: 3.6166x; 3.6166x over previous
//
#include <hip/hip_runtime.h>
#include <math.h>

#define ALPHA_F 0.02f

constexpr int Bn  = 32;
constexpr int Cn  = 512;
constexpr int CRn = 32;    // C / 16
constexpr int HWn = 4096;  // 64*64
constexpr int NCG = 8;     // channel groups of 64 channels
constexpr int NPG = 4;     // pixel groups of 1024 pixels

typedef float floatx4 __attribute__((ext_vector_type(4)));

__device__ __forceinline__ float sigmoidf_(float v) {
    return 1.0f / (1.0f + expf(-v));
}

// ---------------------------------------------------------------------------
// K1: one pass over x. Restructured for load-issue throughput:
//  - channel-INNER load loop: every load independent, per-channel lane
//    partials (csum/cmax) accumulate in registers
//  - batched cross-lane reduce: 8 interleaved shuffle chains (2 halves of 8
//    channels to keep VGPR < 128 / 4-waves-per-SIMD band)
// Block = (b, cg, pg): 64 channels x 1024 pixels. Wave owns 16 channels.
// ---------------------------------------------------------------------------
__global__ __launch_bounds__(256) void k1_reduce(
    const float* __restrict__ x,
    float* __restrict__ cps, float* __restrict__ cpm,
    float* __restrict__ sps, float* __restrict__ spm)
{
    const int bid = blockIdx.x;
    const int pg  = bid & 3;
    const int cg  = (bid >> 2) & 7;
    const int b   = bid >> 5;
    const int t    = threadIdx.x;
    const int wv   = t >> 6;
    const int lane = t & 63;

    __shared__ float ls[4][1024];
    __shared__ float lm[4][1024];

    // wave's 16 rows base
    const float* xw = x + ((size_t)b * Cn + (size_t)cg * 64 + (size_t)wv * 16) * HWn
                        + pg * 1024;

    float4 psum[4], pmax[4];
#pragma unroll
    for (int q = 0; q < 4; ++q) {
        psum[q] = make_float4(0.f, 0.f, 0.f, 0.f);
        pmax[q] = make_float4(-INFINITY, -INFINITY, -INFINITY, -INFINITY);
    }

    const int cbase = (pg * Bn + b) * Cn + cg * 64 + wv * 16;

#pragma unroll
    for (int h = 0; h < 2; ++h) {
        float csum[8], cmax[8];
#pragma unroll
        for (int cl = 0; cl < 8; ++cl) { csum[cl] = 0.f; cmax[cl] = -INFINITY; }

#pragma unroll
        for (int q = 0; q < 4; ++q) {
#pragma unroll
            for (int cl = 0; cl < 8; ++cl) {
                const float4 v =
                    ((const float4*)(xw + (size_t)(h * 8 + cl) * HWn))[q * 64 + lane];
                psum[q].x += v.x; psum[q].y += v.y; psum[q].z += v.z; psum[q].w += v.w;
                pmax[q].x = fmaxf(pmax[q].x, v.x);
                pmax[q].y = fmaxf(pmax[q].y, v.y);
                pmax[q].z = fmaxf(pmax[q].z, v.z);
                pmax[q].w = fmaxf(pmax[q].w, v.w);
                csum[cl] += (v.x + v.y) + (v.z + v.w);
                cmax[cl] = fmaxf(cmax[cl], fmaxf(fmaxf(v.x, v.y), fmaxf(v.z, v.w)));
            }
        }

        // 8 interleaved 6-step shuffle chains (independent -> latency hidden)
#pragma unroll
        for (int m = 32; m >= 1; m >>= 1) {
#pragma unroll
            for (int cl = 0; cl < 8; ++cl) {
                csum[cl] += __shfl_xor(csum[cl], m, 64);
                cmax[cl] = fmaxf(cmax[cl], __shfl_xor(cmax[cl], m, 64));
            }
        }
        // masked writes: lane cl stores channel h*8+cl (compile-time reg index)
#pragma unroll
        for (int cl = 0; cl < 8; ++cl) {
            if (lane == cl) {
                cps[cbase + h * 8 + cl] = csum[cl];
                cpm[cbase + h * 8 + cl] = cmax[cl];
            }
        }
    }

    // stash per-wave pixel partials, combine across the 4 waves
    float4* lsw = (float4*)ls[wv];
    float4* lmw = (float4*)lm[wv];
#pragma unroll
    for (int q = 0; q < 4; ++q) {
        lsw[q * 64 + lane] = psum[q];
        lmw[q * 64 + lane] = pmax[q];
    }
    __syncthreads();

    float4 s  = ((const float4*)ls[0])[t];
    float4 mx = ((const float4*)lm[0])[t];
#pragma unroll
    for (int w = 1; w < 4; ++w) {
        const float4 a  = ((const float4*)ls[w])[t];
        const float4 bb = ((const float4*)lm[w])[t];
        s.x += a.x; s.y += a.y; s.z += a.z; s.w += a.w;
        mx.x = fmaxf(mx.x, bb.x); mx.y = fmaxf(mx.y, bb.y);
        mx.z = fmaxf(mx.z, bb.z); mx.w = fmaxf(mx.w, bb.w);
    }
    float4* os = (float4*)(sps + ((size_t)cg * Bn + b) * HWn + pg * 1024);
    float4* om = (float4*)(spm + ((size_t)cg * Bn + b) * HWn + pg * 1024);
    os[t] = s;
    om[t] = mx;
}

// ---------------------------------------------------------------------------
// K_mid (unchanged from R7): 32 batches x 8 slices; halo-finalize 14-row
// window in LDS, conv own 8 rows; slice-0 runs the channel MLP.
// ---------------------------------------------------------------------------
__global__ __launch_bounds__(256) void k_mid(
    const float* __restrict__ sps, const float* __restrict__ spm,
    const float* __restrict__ cps, const float* __restrict__ cpm,
    const float* __restrict__ w1, const float* __restrict__ w2,
    const float* __restrict__ wconv,
    float* __restrict__ mcF, float* __restrict__ msF)
{
    const int b = blockIdx.x >> 3;
    const int s = blockIdx.x & 7;
    const int t = threadIdx.x;

    __shared__ float wsa[14][64];
    __shared__ float wsm[14][64];
    __shared__ float avg[Cn];
    __shared__ float mxv[Cn];
    __shared__ float hs[CRn];
    __shared__ float wc[98];
    if (t < 98) wc[t] = wconv[t];

    const int ybase = s * 8 - 3;
    {
        const int cgstep = Bn * HWn;
        const float inv = 1.0f / (float)Cn;
#pragma unroll
        for (int k = 0; k < 4; ++k) {
            const int i = t + 256 * k;
            if (i < 14 * 64) {
                const int rw  = i >> 6;
                const int col = i & 63;
                const int yw  = ybase + rw;
                if ((unsigned)yw < 64u) {
                    const int p = (yw << 6) + col;
                    const float* ps = sps + (size_t)b * HWn + p;
                    const float* pm = spm + (size_t)b * HWn + p;
                    float sv = ps[0], mv = pm[0];
#pragma unroll
                    for (int cg = 1; cg < NCG; ++cg) {
                        sv += ps[(size_t)cg * cgstep];
                        mv = fmaxf(mv, pm[(size_t)cg * cgstep]);
                    }
                    wsa[rw][col] = sv * inv;
                    wsm[rw][col] = mv;
                } else {
                    wsa[rw][col] = 0.f;
                    wsm[rw][col] = 0.f;
                }
            }
        }
    }

    if (s == 0) {
        for (int c = t; c < Cn; c += 256) {
            float sv = 0.f, mv = -INFINITY;
#pragma unroll
            for (int pgi = 0; pgi < NPG; ++pgi) {
                sv += cps[(pgi * Bn + b) * Cn + c];
                mv = fmaxf(mv, cpm[(pgi * Bn + b) * Cn + c]);
            }
            avg[c] = sv * (1.0f / (float)HWn);
            mxv[c] = mv;
        }
        __syncthreads();

        const int j = t >> 3, s8 = t & 7;
        float pa = 0.f, pm2 = 0.f;
        const float* w1r = w1 + j * Cn + s8 * 64;
        const float* av  = avg + s8 * 64;
        const float* mv  = mxv + s8 * 64;
        for (int k = 0; k < 64; ++k) {
            pa  += av[k] * w1r[k];
            pm2 += mv[k] * w1r[k];
        }
        pa += __shfl_xor(pa, 1, 64); pm2 += __shfl_xor(pm2, 1, 64);
        pa += __shfl_xor(pa, 2, 64); pm2 += __shfl_xor(pm2, 2, 64);
        pa += __shfl_xor(pa, 4, 64); pm2 += __shfl_xor(pm2, 4, 64);
        if (s8 == 0) hs[j] = fmaxf(pa, 0.f) + fmaxf(pm2, 0.f);
        __syncthreads();

        for (int c = t; c < Cn; c += 256) {
            float o = 0.f;
            const float* w2r = w2 + c * CRn;
#pragma unroll
            for (int jj = 0; jj < CRn; ++jj) o += hs[jj] * w2r[jj];
            mcF[b * Cn + c] = 1.0f - ALPHA_F + ALPHA_F * sigmoidf_(o);
        }
    } else {
        __syncthreads();
        __syncthreads();
    }
    __syncthreads();

#pragma unroll
    for (int k = 0; k < 2; ++k) {
        const int pl  = t + 256 * k;
        const int ry  = pl >> 6;
        const int col = pl & 63;
        const int yown = s * 8 + ry;
        float acc = 0.f;
#pragma unroll
        for (int ky = 0; ky < 7; ++ky) {
            const int yy = yown + ky - 3;
            if ((unsigned)yy >= 64u) continue;
            const int rw = ry + ky;
#pragma unroll
            for (int kx = 0; kx < 7; ++kx) {
                const int xx = col + kx - 3;
                if ((unsigned)xx >= 64u) continue;
                acc += wc[ky * 7 + kx] * wsa[rw][xx]
                     + wc[49 + ky * 7 + kx] * wsm[rw][xx];
            }
        }
        msF[b * HWn + (yown << 6) + col] = 1.0f - ALPHA_F + ALPHA_F * sigmoidf_(acc);
    }
}

// ---------------------------------------------------------------------------
// K4: out = x * mcF[b,c] * msF[b,p]. K1-matched chunk mapping (L2/L3 reuse);
// NT stores keep x L3-resident. Measured ~7.5 TB/s combined — near ceiling.
// ---------------------------------------------------------------------------
__global__ __launch_bounds__(256) void k4_apply(
    const float* __restrict__ x, const float* __restrict__ mcF,
    const float* __restrict__ msF, float* __restrict__ out)
{
    const int bid = blockIdx.x;
    const int pg  = bid & 3;
    const int cg  = (bid >> 2) & 7;
    const int b   = bid >> 5;
    const int t   = threadIdx.x;

    const size_t chunk_off = ((size_t)b * Cn + (size_t)cg * 64) * HWn + pg * 1024;
    const float* xb = x + chunk_off;
    float* ob = out + chunk_off;

    const floatx4 msv = ((const floatx4*)(msF + (size_t)b * HWn + pg * 1024))[t];
    const float* mcRow = mcF + b * Cn + cg * 64;

#pragma unroll 8
    for (int r = 0; r < 64; ++r) {
        const floatx4 xv = ((const floatx4*)(xb + (size_t)r * HWn))[t];
        const floatx4 res = xv * (mcRow[r] * msv);
        __builtin_nontemporal_store(res, ((floatx4*)(ob + (size_t)r * HWn)) + t);
    }
}

extern "C" void kernel_launch(void* const* d_in, const int* in_sizes, int n_in,
                              void* d_out, int out_size, void* d_ws, size_t ws_size,
                              hipStream_t stream)
{
    const float* x     = (const float*)d_in[0];
    const float* w1    = (const float*)d_in[1];
    const float* w2    = (const float*)d_in[2];
    const float* wconv = (const float*)d_in[3];
    float* out = (float*)d_out;

    float* p = (float*)d_ws;
    float* cps  = p; p += NPG * Bn * Cn;   // 65536
    float* cpm  = p; p += NPG * Bn * Cn;   // 65536
    float* sps  = p; p += NCG * Bn * HWn;  // 1048576
    float* spm  = p; p += NCG * Bn * HWn;  // 1048576
    float* mcF  = p; p += Bn * Cn;         // 16384
    float* msF  = p; p += Bn * HWn;        // 131072

    hipLaunchKernelGGL(k1_reduce, dim3(Bn * NCG * NPG), dim3(256), 0, stream,
                       x, cps, cpm, sps, spm);
    hipLaunchKernelGGL(k_mid, dim3(Bn * 8), dim3(256), 0, stream,
                       sps, spm, cps, cpm, w1, w2, wconv, mcF, msF);
    hipLaunchKernelGGL(k4_apply, dim3(Bn * NCG * NPG), dim3(256), 0, stream,
                       x, mcF, msF, out);
}

// Round 10
// 158.536 us; speedup vs baseline: 3.8418x; 1.0623x over previous
//
#include <hip/hip_runtime.h>
#include <math.h>

#define ALPHA_F 0.02f

constexpr int Bn  = 32;
constexpr int Cn  = 512;
constexpr int CRn = 32;    // C / 16
constexpr int HWn = 4096;  // 64*64
constexpr int NCG = 8;     // channel groups of 64 channels
constexpr int NPG = 4;     // pixel groups of 1024 pixels

typedef float floatx4 __attribute__((ext_vector_type(4)));

__device__ __forceinline__ float sigmoidf_(float v) {
    return 1.0f / (1.0f + expf(-v));
}

// ---------------------------------------------------------------------------
// K1: one pass over x. Channel reduction via LDS transpose (NO cross-lane
// shuffle chains — R8 showed the 192 serial ds_bpermute ops were ~12 µs/CU):
//   Phase A: per (channel, lane) partials -> LDS [64][65] (padded, no bank
//            conflicts; uniform-row writes are 2-way = free)
//   Phase B: transpose-reduce: thread (c, quarter) sums 16 lanes (independent
//            ds_read_b32), 2-stage -> cps/cpm
//   Phase C: pixel partials combined across waves (proven R7 path, LDS reused)
// Block = (b, cg, pg): 64 channels x 1024 pixels. Wave owns 16 channels.
// ---------------------------------------------------------------------------
__global__ __launch_bounds__(256) void k1_reduce(
    const float* __restrict__ x,
    float* __restrict__ cps, float* __restrict__ cpm,
    float* __restrict__ sps, float* __restrict__ spm)
{
    const int bid = blockIdx.x;
    const int pg  = bid & 3;
    const int cg  = (bid >> 2) & 7;
    const int b   = bid >> 5;
    const int t    = threadIdx.x;
    const int wv   = t >> 6;
    const int lane = t & 63;

    __shared__ union {
        struct { float cs[64 * 65]; float cm[64 * 65]; } a;      // 33.3 KB
        struct { float ls[4][1024]; float lm[4][1024]; } c;      // 32 KB
    } u;
    __shared__ float ps2[4 * 64];
    __shared__ float pm2[4 * 64];

    // wave's 16 rows base
    const float* xw = x + ((size_t)b * Cn + (size_t)cg * 64 + (size_t)wv * 16) * HWn
                        + pg * 1024;

    float4 psum[4], pmax[4];
#pragma unroll
    for (int q = 0; q < 4; ++q) {
        psum[q] = make_float4(0.f, 0.f, 0.f, 0.f);
        pmax[q] = make_float4(-INFINITY, -INFINITY, -INFINITY, -INFINITY);
    }

    // ---- Phase A: accumulate; per-(channel,lane) partials to LDS ----
#pragma unroll 4
    for (int cl = 0; cl < 16; ++cl) {
        const float4* row = (const float4*)(xw + (size_t)cl * HWn);
        float lsum = 0.f, lmax = -INFINITY;
#pragma unroll
        for (int q = 0; q < 4; ++q) {
            const float4 v = row[q * 64 + lane];
            psum[q].x += v.x; psum[q].y += v.y; psum[q].z += v.z; psum[q].w += v.w;
            pmax[q].x = fmaxf(pmax[q].x, v.x);
            pmax[q].y = fmaxf(pmax[q].y, v.y);
            pmax[q].z = fmaxf(pmax[q].z, v.z);
            pmax[q].w = fmaxf(pmax[q].w, v.w);
            lsum += (v.x + v.y) + (v.z + v.w);
            lmax = fmaxf(lmax, fmaxf(fmaxf(v.x, v.y), fmaxf(v.z, v.w)));
        }
        const int ch = wv * 16 + cl;   // wave-uniform row
        u.a.cs[ch * 65 + lane] = lsum;
        u.a.cm[ch * 65 + lane] = lmax;
    }
    __syncthreads();

    // ---- Phase B1: thread (c = t&63, qd = t>>6) reduces 16 lane-partials ----
    {
        const int c  = t & 63;
        const int qd = t >> 6;
        const float* pcs = u.a.cs + c * 65 + qd * 16;
        const float* pcm = u.a.cm + c * 65 + qd * 16;
        float s = 0.f, m = -INFINITY;
#pragma unroll
        for (int i = 0; i < 16; ++i) {
            s += pcs[i];
            m = fmaxf(m, pcm[i]);
        }
        ps2[qd * 64 + c] = s;
        pm2[qd * 64 + c] = m;
    }
    __syncthreads();

    // ---- Phase C1: pixel partials into reused LDS (cs/cm dead now) ----
    {
        float4* lsw = (float4*)u.c.ls[wv];
        float4* lmw = (float4*)u.c.lm[wv];
#pragma unroll
        for (int q = 0; q < 4; ++q) {
            lsw[q * 64 + lane] = psum[q];
            lmw[q * 64 + lane] = pmax[q];
        }
    }
    // ---- Phase B2: final channel reduce + global write (t < 64) ----
    if (t < 64) {
        const float s = (ps2[t] + ps2[64 + t]) + (ps2[128 + t] + ps2[192 + t]);
        const float m = fmaxf(fmaxf(pm2[t], pm2[64 + t]),
                              fmaxf(pm2[128 + t], pm2[192 + t]));
        const int cglob = cg * 64 + t;
        cps[(pg * Bn + b) * Cn + cglob] = s;
        cpm[(pg * Bn + b) * Cn + cglob] = m;
    }
    __syncthreads();

    // ---- Phase C2: combine the 4 waves' pixel partials (R7 path) ----
    float4 s  = ((const float4*)u.c.ls[0])[t];
    float4 mx = ((const float4*)u.c.lm[0])[t];
#pragma unroll
    for (int w = 1; w < 4; ++w) {
        const float4 a  = ((const float4*)u.c.ls[w])[t];
        const float4 bb = ((const float4*)u.c.lm[w])[t];
        s.x += a.x; s.y += a.y; s.z += a.z; s.w += a.w;
        mx.x = fmaxf(mx.x, bb.x); mx.y = fmaxf(mx.y, bb.y);
        mx.z = fmaxf(mx.z, bb.z); mx.w = fmaxf(mx.w, bb.w);
    }
    float4* os = (float4*)(sps + ((size_t)cg * Bn + b) * HWn + pg * 1024);
    float4* om = (float4*)(spm + ((size_t)cg * Bn + b) * HWn + pg * 1024);
    os[t] = s;
    om[t] = mx;
}

// ---------------------------------------------------------------------------
// K_mid (unchanged from R7): 32 batches x 8 slices; halo-finalize 14-row
// window in LDS, conv own 8 rows; slice-0 runs the channel MLP.
// ---------------------------------------------------------------------------
__global__ __launch_bounds__(256) void k_mid(
    const float* __restrict__ sps, const float* __restrict__ spm,
    const float* __restrict__ cps, const float* __restrict__ cpm,
    const float* __restrict__ w1, const float* __restrict__ w2,
    const float* __restrict__ wconv,
    float* __restrict__ mcF, float* __restrict__ msF)
{
    const int b = blockIdx.x >> 3;
    const int s = blockIdx.x & 7;
    const int t = threadIdx.x;

    __shared__ float wsa[14][64];
    __shared__ float wsm[14][64];
    __shared__ float avg[Cn];
    __shared__ float mxv[Cn];
    __shared__ float hs[CRn];
    __shared__ float wc[98];
    if (t < 98) wc[t] = wconv[t];

    const int ybase = s * 8 - 3;
    {
        const int cgstep = Bn * HWn;
        const float inv = 1.0f / (float)Cn;
#pragma unroll
        for (int k = 0; k < 4; ++k) {
            const int i = t + 256 * k;
            if (i < 14 * 64) {
                const int rw  = i >> 6;
                const int col = i & 63;
                const int yw  = ybase + rw;
                if ((unsigned)yw < 64u) {
                    const int p = (yw << 6) + col;
                    const float* ps = sps + (size_t)b * HWn + p;
                    const float* pm = spm + (size_t)b * HWn + p;
                    float sv = ps[0], mv = pm[0];
#pragma unroll
                    for (int cg = 1; cg < NCG; ++cg) {
                        sv += ps[(size_t)cg * cgstep];
                        mv = fmaxf(mv, pm[(size_t)cg * cgstep]);
                    }
                    wsa[rw][col] = sv * inv;
                    wsm[rw][col] = mv;
                } else {
                    wsa[rw][col] = 0.f;
                    wsm[rw][col] = 0.f;
                }
            }
        }
    }

    if (s == 0) {
        for (int c = t; c < Cn; c += 256) {
            float sv = 0.f, mv = -INFINITY;
#pragma unroll
            for (int pgi = 0; pgi < NPG; ++pgi) {
                sv += cps[(pgi * Bn + b) * Cn + c];
                mv = fmaxf(mv, cpm[(pgi * Bn + b) * Cn + c]);
            }
            avg[c] = sv * (1.0f / (float)HWn);
            mxv[c] = mv;
        }
        __syncthreads();

        const int j = t >> 3, s8 = t & 7;
        float pa = 0.f, pm2 = 0.f;
        const float* w1r = w1 + j * Cn + s8 * 64;
        const float* av  = avg + s8 * 64;
        const float* mv  = mxv + s8 * 64;
        for (int k = 0; k < 64; ++k) {
            pa  += av[k] * w1r[k];
            pm2 += mv[k] * w1r[k];
        }
        pa += __shfl_xor(pa, 1, 64); pm2 += __shfl_xor(pm2, 1, 64);
        pa += __shfl_xor(pa, 2, 64); pm2 += __shfl_xor(pm2, 2, 64);
        pa += __shfl_xor(pa, 4, 64); pm2 += __shfl_xor(pm2, 4, 64);
        if (s8 == 0) hs[j] = fmaxf(pa, 0.f) + fmaxf(pm2, 0.f);
        __syncthreads();

        for (int c = t; c < Cn; c += 256) {
            float o = 0.f;
            const float* w2r = w2 + c * CRn;
#pragma unroll
            for (int jj = 0; jj < CRn; ++jj) o += hs[jj] * w2r[jj];
            mcF[b * Cn + c] = 1.0f - ALPHA_F + ALPHA_F * sigmoidf_(o);
        }
    } else {
        __syncthreads();
        __syncthreads();
    }
    __syncthreads();

#pragma unroll
    for (int k = 0; k < 2; ++k) {
        const int pl  = t + 256 * k;
        const int ry  = pl >> 6;
        const int col = pl & 63;
        const int yown = s * 8 + ry;
        float acc = 0.f;
#pragma unroll
        for (int ky = 0; ky < 7; ++ky) {
            const int yy = yown + ky - 3;
            if ((unsigned)yy >= 64u) continue;
            const int rw = ry + ky;
#pragma unroll
            for (int kx = 0; kx < 7; ++kx) {
                const int xx = col + kx - 3;
                if ((unsigned)xx >= 64u) continue;
                acc += wc[ky * 7 + kx] * wsa[rw][xx]
                     + wc[49 + ky * 7 + kx] * wsm[rw][xx];
            }
        }
        msF[b * HWn + (yown << 6) + col] = 1.0f - ALPHA_F + ALPHA_F * sigmoidf_(acc);
    }
}

// ---------------------------------------------------------------------------
// K4: out = x * mcF[b,c] * msF[b,p]. K1-matched chunk mapping (L2/L3 reuse);
// NT stores keep x L3-resident. Measured ~7.5 TB/s combined — near ceiling.
// ---------------------------------------------------------------------------
__global__ __launch_bounds__(256) void k4_apply(
    const float* __restrict__ x, const float* __restrict__ mcF,
    const float* __restrict__ msF, float* __restrict__ out)
{
    const int bid = blockIdx.x;
    const int pg  = bid & 3;
    const int cg  = (bid >> 2) & 7;
    const int b   = bid >> 5;
    const int t   = threadIdx.x;

    const size_t chunk_off = ((size_t)b * Cn + (size_t)cg * 64) * HWn + pg * 1024;
    const float* xb = x + chunk_off;
    float* ob = out + chunk_off;

    const floatx4 msv = ((const floatx4*)(msF + (size_t)b * HWn + pg * 1024))[t];
    const float* mcRow = mcF + b * Cn + cg * 64;

#pragma unroll 8
    for (int r = 0; r < 64; ++r) {
        const floatx4 xv = ((const floatx4*)(xb + (size_t)r * HWn))[t];
        const floatx4 res = xv * (mcRow[r] * msv);
        __builtin_nontemporal_store(res, ((floatx4*)(ob + (size_t)r * HWn)) + t);
    }
}

extern "C" void kernel_launch(void* const* d_in, const int* in_sizes, int n_in,
                              void* d_out, int out_size, void* d_ws, size_t ws_size,
                              hipStream_t stream)
{
    const float* x     = (const float*)d_in[0];
    const float* w1    = (const float*)d_in[1];
    const float* w2    = (const float*)d_in[2];
    const float* wconv = (const float*)d_in[3];
    float* out = (float*)d_out;

    float* p = (float*)d_ws;
    float* cps  = p; p += NPG * Bn * Cn;   // 65536
    float* cpm  = p; p += NPG * Bn * Cn;   // 65536
    float* sps  = p; p += NCG * Bn * HWn;  // 1048576
    float* spm  = p; p += NCG * Bn * HWn;  // 1048576
    float* mcF  = p; p += Bn * Cn;         // 16384
    float* msF  = p; p += Bn * HWn;        // 131072

    hipLaunchKernelGGL(k1_reduce, dim3(Bn * NCG * NPG), dim3(256), 0, stream,
                       x, cps, cpm, sps, spm);
    hipLaunchKernelGGL(k_mid, dim3(Bn * 8), dim3(256), 0, stream,
                       sps, spm, cps, cpm, w1, w2, wconv, mcF, msF);
    hipLaunchKernelGGL(k4_apply, dim3(Bn * NCG * NPG), dim3(256), 0, stream,
                       x, mcF, msF, out);
}

// Round 11
// 153.145 us; speedup vs baseline: 3.9770x; 1.0352x over previous
//
#include <hip/hip_runtime.h>
#include <math.h>

#define ALPHA_F 0.02f

constexpr int Bn  = 32;
constexpr int Cn  = 512;
constexpr int CRn = 32;    // C / 16
constexpr int HWn = 4096;  // 64*64
constexpr int NCG = 8;     // channel groups of 64 channels
constexpr int NPG = 4;     // pixel groups of 1024 pixels

typedef float floatx4 __attribute__((ext_vector_type(4)));

__device__ __forceinline__ float sigmoidf_(float v) {
    return 1.0f / (1.0f + expf(-v));
}

// ---------------------------------------------------------------------------
// K1: one pass over x. Computes
//   cps/cpm: channel partial sum/max  [NPG][B][C]   (partial over 1024 pixels)
//   sps/spm: spatial partial sum/max  [NCG][B][HW]  (partial over 64 channels)
// Block = (b, cg, pg): 64 channels x 1024 pixels. 4 waves; wave owns 16 chans.
// NOTE: three reduction structures tried (R7 shuffle-serial / R9 interleaved /
// R10 LDS-transpose); this one is empirically fastest — K1 is ramp/latency
// limited, not reduce-limited.
// ---------------------------------------------------------------------------
__global__ __launch_bounds__(256) void k1_reduce(
    const float* __restrict__ x,
    float* __restrict__ cps, float* __restrict__ cpm,
    float* __restrict__ sps, float* __restrict__ spm)
{
    const int bid = blockIdx.x;
    const int pg  = bid & 3;
    const int cg  = (bid >> 2) & 7;
    const int b   = bid >> 5;
    const int t    = threadIdx.x;
    const int wv   = t >> 6;
    const int lane = t & 63;

    __shared__ float ls[4][1024];
    __shared__ float lm[4][1024];

    const float* xb = x + ((size_t)b * Cn + (size_t)cg * 64) * HWn + pg * 1024;

    // per-pixel accumulators: pixel_local = 256*q + 4*lane + i
    float4 psum[4], pmax[4];
#pragma unroll
    for (int q = 0; q < 4; ++q) {
        psum[q] = make_float4(0.f, 0.f, 0.f, 0.f);
        pmax[q] = make_float4(-INFINITY, -INFINITY, -INFINITY, -INFINITY);
    }

#pragma unroll 4
    for (int cl = 0; cl < 16; ++cl) {
        const int c = wv * 16 + cl;  // channel within the 64-ch group
        const float4* row = (const float4*)(xb + (size_t)c * HWn);
        float lsum = 0.f, lmax = -INFINITY;
#pragma unroll
        for (int q = 0; q < 4; ++q) {
            const float4 v = row[q * 64 + lane];
            psum[q].x += v.x; psum[q].y += v.y; psum[q].z += v.z; psum[q].w += v.w;
            pmax[q].x = fmaxf(pmax[q].x, v.x);
            pmax[q].y = fmaxf(pmax[q].y, v.y);
            pmax[q].z = fmaxf(pmax[q].z, v.z);
            pmax[q].w = fmaxf(pmax[q].w, v.w);
            lsum += (v.x + v.y) + (v.z + v.w);
            lmax = fmaxf(lmax, fmaxf(fmaxf(v.x, v.y), fmaxf(v.z, v.w)));
        }
        // wave-level reduce over 64 lanes -> partial over 1024 pixels
#pragma unroll
        for (int m = 32; m >= 1; m >>= 1) {
            lsum += __shfl_xor(lsum, m, 64);
            lmax = fmaxf(lmax, __shfl_xor(lmax, m, 64));
        }
        if (lane == 0) {
            const int cglob = cg * 64 + c;
            cps[(pg * Bn + b) * Cn + cglob] = lsum;
            cpm[(pg * Bn + b) * Cn + cglob] = lmax;
        }
    }

    // stash per-wave pixel partials, combine across the 4 waves
    float4* lsw = (float4*)ls[wv];
    float4* lmw = (float4*)lm[wv];
#pragma unroll
    for (int q = 0; q < 4; ++q) {
        lsw[q * 64 + lane] = psum[q];
        lmw[q * 64 + lane] = pmax[q];
    }
    __syncthreads();

    float4 s  = ((const float4*)ls[0])[t];
    float4 mx = ((const float4*)lm[0])[t];
#pragma unroll
    for (int w = 1; w < 4; ++w) {
        const float4 a  = ((const float4*)ls[w])[t];
        const float4 bb = ((const float4*)lm[w])[t];
        s.x += a.x; s.y += a.y; s.z += a.z; s.w += a.w;
        mx.x = fmaxf(mx.x, bb.x); mx.y = fmaxf(mx.y, bb.y);
        mx.z = fmaxf(mx.z, bb.z); mx.w = fmaxf(mx.w, bb.w);
    }
    float4* os = (float4*)(sps + ((size_t)cg * Bn + b) * HWn + pg * 1024);
    float4* om = (float4*)(spm + ((size_t)cg * Bn + b) * HWn + pg * 1024);
    os[t] = s;
    om[t] = mx;
}

// ---------------------------------------------------------------------------
// K_mid (fused k2a+k2b+k3): grid = 32 batches x 8 pixel-slices, 256 threads.
// Each block: halo-finalize a 14-row window of spatial partials into LDS,
// 7x7-conv its own 8 rows -> msF. Slice-0 blocks additionally run the
// channel MLP -> mcF (block-uniform branch).
// ---------------------------------------------------------------------------
__global__ __launch_bounds__(256) void k_mid(
    const float* __restrict__ sps, const float* __restrict__ spm,
    const float* __restrict__ cps, const float* __restrict__ cpm,
    const float* __restrict__ w1, const float* __restrict__ w2,
    const float* __restrict__ wconv,
    float* __restrict__ mcF, float* __restrict__ msF)
{
    const int b = blockIdx.x >> 3;
    const int s = blockIdx.x & 7;   // pixel slice: own rows [8s, 8s+8)
    const int t = threadIdx.x;

    __shared__ float wsa[14][64];
    __shared__ float wsm[14][64];
    __shared__ float avg[Cn];
    __shared__ float mxv[Cn];
    __shared__ float hs[CRn];
    __shared__ float wc[98];
    if (t < 98) wc[t] = wconv[t];

    // A) halo finalize: window rows yw in [8s-3, 8s+11), 14 rows x 64 cols
    const int ybase = s * 8 - 3;
    {
        const int cgstep = Bn * HWn;  // float stride between cg planes
        const float inv = 1.0f / (float)Cn;
#pragma unroll
        for (int k = 0; k < 4; ++k) {
            const int i = t + 256 * k;       // 0..895 window-local px
            if (i < 14 * 64) {
                const int rw  = i >> 6;
                const int col = i & 63;
                const int yw  = ybase + rw;
                if ((unsigned)yw < 64u) {
                    const int p = (yw << 6) + col;
                    const float* ps = sps + (size_t)b * HWn + p;
                    const float* pm = spm + (size_t)b * HWn + p;
                    float sv = ps[0], mv = pm[0];
#pragma unroll
                    for (int cg = 1; cg < NCG; ++cg) {
                        sv += ps[(size_t)cg * cgstep];
                        mv = fmaxf(mv, pm[(size_t)cg * cgstep]);
                    }
                    wsa[rw][col] = sv * inv;
                    wsm[rw][col] = mv;
                } else {
                    wsa[rw][col] = 0.f;
                    wsm[rw][col] = 0.f;
                }
            }
        }
    }

    // B) channel MLP, slice-0 blocks only (block-uniform condition)
    if (s == 0) {
        for (int c = t; c < Cn; c += 256) {
            float sv = 0.f, mv = -INFINITY;
#pragma unroll
            for (int pgi = 0; pgi < NPG; ++pgi) {
                sv += cps[(pgi * Bn + b) * Cn + c];
                mv = fmaxf(mv, cpm[(pgi * Bn + b) * Cn + c]);
            }
            avg[c] = sv * (1.0f / (float)HWn);
            mxv[c] = mv;
        }
        __syncthreads();

        const int j = t >> 3, s8 = t & 7;
        float pa = 0.f, pm2 = 0.f;
        const float* w1r = w1 + j * Cn + s8 * 64;
        const float* av  = avg + s8 * 64;
        const float* mv  = mxv + s8 * 64;
        for (int k = 0; k < 64; ++k) {
            pa  += av[k] * w1r[k];
            pm2 += mv[k] * w1r[k];
        }
        pa += __shfl_xor(pa, 1, 64); pm2 += __shfl_xor(pm2, 1, 64);
        pa += __shfl_xor(pa, 2, 64); pm2 += __shfl_xor(pm2, 2, 64);
        pa += __shfl_xor(pa, 4, 64); pm2 += __shfl_xor(pm2, 4, 64);
        if (s8 == 0) hs[j] = fmaxf(pa, 0.f) + fmaxf(pm2, 0.f);
        __syncthreads();

        for (int c = t; c < Cn; c += 256) {
            float o = 0.f;
            const float* w2r = w2 + c * CRn;
#pragma unroll
            for (int jj = 0; jj < CRn; ++jj) o += hs[jj] * w2r[jj];
            mcF[b * Cn + c] = 1.0f - ALPHA_F + ALPHA_F * sigmoidf_(o);
        }
    } else {
        __syncthreads();
        __syncthreads();
    }
    __syncthreads();

    // C) 7x7 conv over own 8 rows (512 px, 2 per thread) from LDS window
#pragma unroll
    for (int k = 0; k < 2; ++k) {
        const int pl  = t + 256 * k;        // 0..511 own-local px
        const int ry  = pl >> 6;            // own row 0..7
        const int col = pl & 63;
        const int yown = s * 8 + ry;
        float acc = 0.f;
#pragma unroll
        for (int ky = 0; ky < 7; ++ky) {
            const int yy = yown + ky - 3;
            if ((unsigned)yy >= 64u) continue;
            const int rw = ry + ky;         // yy - ybase
#pragma unroll
            for (int kx = 0; kx < 7; ++kx) {
                const int xx = col + kx - 3;
                if ((unsigned)xx >= 64u) continue;
                acc += wc[ky * 7 + kx] * wsa[rw][xx]
                     + wc[49 + ky * 7 + kx] * wsm[rw][xx];
            }
        }
        msF[b * HWn + (yown << 6) + col] = 1.0f - ALPHA_F + ALPHA_F * sigmoidf_(acc);
    }
}

// ---------------------------------------------------------------------------
// K4: out = x * mcF[b,c] * msF[b,p]. Same (b,cg,pg) chunk mapping as K1 so
// the block re-reads what its XCD's L2/L3 already holds; NT stores so `out`
// doesn't evict x (x = 256 MB = exactly the Infinity Cache).
// Measured ~7.5 TB/s combined R+W (R8 mega) — at the streaming ceiling.
// ---------------------------------------------------------------------------
__global__ __launch_bounds__(256) void k4_apply(
    const float* __restrict__ x, const float* __restrict__ mcF,
    const float* __restrict__ msF, float* __restrict__ out)
{
    const int bid = blockIdx.x;
    const int pg  = bid & 3;
    const int cg  = (bid >> 2) & 7;
    const int b   = bid >> 5;
    const int t   = threadIdx.x;

    const size_t chunk_off = ((size_t)b * Cn + (size_t)cg * 64) * HWn + pg * 1024;
    const float* xb = x + chunk_off;
    float* ob = out + chunk_off;

    const floatx4 msv = ((const floatx4*)(msF + (size_t)b * HWn + pg * 1024))[t];
    const float* mcRow = mcF + b * Cn + cg * 64;

#pragma unroll 8
    for (int r = 0; r < 64; ++r) {
        const floatx4 xv = ((const floatx4*)(xb + (size_t)r * HWn))[t];
        const floatx4 res = xv * (mcRow[r] * msv);
        __builtin_nontemporal_store(res, ((floatx4*)(ob + (size_t)r * HWn)) + t);
    }
}

extern "C" void kernel_launch(void* const* d_in, const int* in_sizes, int n_in,
                              void* d_out, int out_size, void* d_ws, size_t ws_size,
                              hipStream_t stream)
{
    const float* x     = (const float*)d_in[0];
    const float* w1    = (const float*)d_in[1];
    const float* w2    = (const float*)d_in[2];
    const float* wconv = (const float*)d_in[3];
    float* out = (float*)d_out;

    float* p = (float*)d_ws;
    float* cps  = p; p += NPG * Bn * Cn;   // 65536
    float* cpm  = p; p += NPG * Bn * Cn;   // 65536
    float* sps  = p; p += NCG * Bn * HWn;  // 1048576
    float* spm  = p; p += NCG * Bn * HWn;  // 1048576
    float* mcF  = p; p += Bn * Cn;         // 16384
    float* msF  = p; p += Bn * HWn;        // 131072

    hipLaunchKernelGGL(k1_reduce, dim3(Bn * NCG * NPG), dim3(256), 0, stream,
                       x, cps, cpm, sps, spm);
    hipLaunchKernelGGL(k_mid, dim3(Bn * 8), dim3(256), 0, stream,
                       sps, spm, cps, cpm, w1, w2, wconv, mcF, msF);
    hipLaunchKernelGGL(k4_apply, dim3(Bn * NCG * NPG), dim3(256), 0, stream,
                       x, mcF, msF, out);
}